// Round 11
// baseline (184.812 us; speedup 1.0000x reference)
//
#include <hip/hip_runtime.h>

#define N_ROWS 32768
#define DIM    256
#define KCODES 2048
#define CSCALE 4096.0f
#define CG     16                 // code splits (128 codes per block, 32 per wave)
#define YS     48                 // row-range splits; CG*YS = 768 = 3 blocks/CU
#define NSLOT  (CG * 4)           // 64 partial slots per row

typedef __attribute__((ext_vector_type(16))) float f32x16;
typedef __attribute__((ext_vector_type(4)))  unsigned int u32x4;
union frag16 { u32x4 v; long l[2]; };

// Piece layout (per 64B k-chunk): piece d (=h*2+q, 16B) holds the two 8B MFMA
// fragments (ks=2q,2q+1) for k-half h:
//   bytes [0,8)  = k = q*32      + h*8 + [0,8)
//   bytes [8,16) = k = q*32 + 16 + h*8 + [0,8)

// ---------------- prologue A: cb -> fp8 (x4096) piece layout + halfcn -----------
__global__ void prep_cb(const float* __restrict__ cb, unsigned int* __restrict__ cbf8,
                        float* __restrict__ halfcn, float* __restrict__ loss) {
    const int t    = threadIdx.x;            // 256 thr = 4 codes x 64 dword slots
    const int code = blockIdx.x * 4 + (t >> 6);
    const int s    = t & 63;
    if (blockIdx.x == 0 && t == 0) *loss = 0.0f;
    const int kc = s >> 4, d = (s >> 2) & 3, b4 = (s & 3) * 4;
    const int h = d >> 1, q = d & 1;
    const int k0 = kc * 64 + q * 32 + (b4 >> 3) * 16 + h * 8 + (b4 & 7);
    float4 v = *(const float4*)&cb[(size_t)code * DIM + k0];
    int pk = __builtin_amdgcn_cvt_pk_fp8_f32(v.x * CSCALE, v.y * CSCALE, 0, false);
    pk     = __builtin_amdgcn_cvt_pk_fp8_f32(v.z * CSCALE, v.w * CSCALE, pk, true);
    cbf8[(size_t)code * 64 + s] = (unsigned int)pk;
    float ssum = v.x * v.x + v.y * v.y + v.z * v.z + v.w * v.w;
    #pragma unroll
    for (int o = 32; o > 0; o >>= 1) ssum += __shfl_down(ssum, o, 64);
    if (s == 0) halfcn[code] = 0.5f * CSCALE * ssum;
}

// ---------------- prologue B: x -> fp8 piece layout (into d_out scratch) --------
__global__ void prep_x(const float* __restrict__ x, unsigned int* __restrict__ x8) {
    const int t   = threadIdx.x;             // 256 thr = 4 rows x 64 dword slots
    const int row = blockIdx.x * 4 + (t >> 6);
    const int s   = t & 63;
    const int kc = s >> 4, d = (s >> 2) & 3, b4 = (s & 3) * 4;
    const int h = d >> 1, q = d & 1;
    const int k0 = kc * 64 + q * 32 + (b4 >> 3) * 16 + h * 8 + (b4 & 7);
    float4 v = *(const float4*)&x[(size_t)row * DIM + k0];
    int pk = __builtin_amdgcn_cvt_pk_fp8_f32(v.x, v.y, 0, false);
    pk     = __builtin_amdgcn_cvt_pk_fp8_f32(v.z, v.w, pk, true);
    x8[(size_t)row * 64 + s] = (unsigned int)pk;
}

// ---------------- main: codes-in-registers, zero-LDS, barrier-free --------------
// A operand = this wave's 32 codes (32 VGPRs, loaded once). B operand = x rows,
// 16 global dwordx4 per 64-row step feeding 32 MFMAs. C[m=code][n=row] means the
// per-row argmax is an IN-LANE reduce over 16 regs (+1 shfl_xor(32) across the
// h code-halves). One coalesced partial store per row-tile. No LDS, no barriers.
__global__ __launch_bounds__(256, 3) void vq_argmin(
        const char* __restrict__ x8, const char* __restrict__ cbf8,
        const float* __restrict__ halfcn, float* __restrict__ part) {
    const int t    = threadIdx.x;
    const int lane = t & 63;
    const int w    = t >> 6;
    const int l32  = lane & 31;
    const int h    = lane >> 5;
    const int cg   = blockIdx.x;             // 0..CG-1
    const int by   = blockIdx.y;             // 0..YS-1
    const int code0 = cg * 128 + w * 32;     // wave's 32 codes

    // ---- codebook fragments -> registers (loaded once; 32 VGPRs) ----
    frag16 cf[4][2];
    {
        const char* cbase = cbf8 + (size_t)(code0 + l32) * DIM;
        #pragma unroll
        for (int kc = 0; kc < 4; kc++)
            #pragma unroll
            for (int q = 0; q < 2; q++)
                cf[kc][q].v = *(const u32x4*)(cbase + kc * 64 + (h * 2 + q) * 16);
    }

    // ---- bias: halfcn for reg r -> code m=(r&3)+8*(r>>2)+4h (16 VGPRs) ----
    float bias[16];
    #pragma unroll
    for (int g = 0; g < 4; g++)
        *(float4*)&bias[g * 4] = *(const float4*)&halfcn[code0 + g * 8 + 4 * h];

    const unsigned codebase = (unsigned)(code0 + 4 * h);

    const int s0 = (by * 512) / YS;          // 512 total 64-row steps
    const int s1 = ((by + 1) * 512) / YS;

    for (int s = s0; s < s1; ++s) {
        const int r0 = s * 64;
        // ---- x fragments for 64 rows: 16 dwordx4 straight from global ----
        frag16 xf[2][4][2];
        const char* xb0 = x8 + (size_t)(r0 + l32) * DIM;
        const char* xb1 = x8 + (size_t)(r0 + 32 + l32) * DIM;
        #pragma unroll
        for (int kc = 0; kc < 4; kc++)
            #pragma unroll
            for (int q = 0; q < 2; q++) {
                xf[0][kc][q].v = *(const u32x4*)(xb0 + kc * 64 + (h * 2 + q) * 16);
                xf[1][kc][q].v = *(const u32x4*)(xb1 + kc * 64 + (h * 2 + q) * 16);
            }

        f32x16 acc[2];
        #pragma unroll
        for (int r = 0; r < 16; r++) {
            acc[0][r] = -bias[r];
            acc[1][r] = -bias[r];
        }

        #pragma unroll
        for (int kc = 0; kc < 4; kc++)
            #pragma unroll
            for (int q = 0; q < 2; q++)
                #pragma unroll
                for (int sl = 0; sl < 2; sl++)
                    #pragma unroll
                    for (int rt = 0; rt < 2; rt++)
                        acc[rt] = __builtin_amdgcn_mfma_f32_32x32x16_fp8_fp8(
                            cf[kc][q].l[sl], xf[rt][kc][q].l[sl], acc[rt], 0, 0, 0);

        // ---- per-row argmax: in-lane over 16 regs, then across h halves ----
        #pragma unroll
        for (int rt = 0; rt < 2; rt++) {
            float best = -3.0e38f;
            #pragma unroll
            for (int r = 0; r < 16; r++) {
                const unsigned code = codebase + (unsigned)((r & 3) + 8 * (r >> 2));
                const unsigned u = (__float_as_uint(acc[rt][r]) & 0xFFFFF800u) | code;
                best = fmaxf(best, __uint_as_float(u));
            }
            best = fmaxf(best, __shfl_xor(best, 32, 64));
            if (h == 0)
                part[(size_t)(cg * 4 + w) * N_ROWS + r0 + rt * 32 + l32] = best;
        }
    }
}

// ---------------- finish: reduce 64 partials/row + gather + loss ----------------
__global__ void finish_kernel(const float* __restrict__ x, const float* __restrict__ cb,
                              const float* __restrict__ part, float* __restrict__ out,
                              float* __restrict__ loss) {
    __shared__ int idxs[256];
    __shared__ float lred[4];
    const int t    = threadIdx.x;
    const int row0 = blockIdx.x * 256;

    // phase 1: per-row argmax over the 64 slots (coalesced column reads)
    {
        const int row = row0 + t;
        float best = part[row];
        #pragma unroll 8
        for (int sl = 1; sl < NSLOT; sl++)
            best = fmaxf(best, part[(size_t)sl * N_ROWS + row]);
        idxs[t] = (int)(__float_as_uint(best) & 2047u);
    }
    __syncthreads();

    // phase 2: gather fp32 code vectors + loss partial (t = dim)
    float lsum = 0.0f;
    #pragma unroll 4
    for (int r = 0; r < 256; r++) {
        const int code = idxs[r];
        const float c  = cb[(size_t)code * DIM + t];
        const float xv = x[(size_t)(row0 + r) * DIM + t];
        out[(size_t)(row0 + r) * DIM + t] = c;
        const float d = xv - c;
        lsum += d * d;
    }
    #pragma unroll
    for (int o = 32; o > 0; o >>= 1) lsum += __shfl_down(lsum, o, 64);
    if ((t & 63) == 0) lred[t >> 6] = lsum;
    __syncthreads();
    if (t == 0) {
        const float scale = 1.25f / (float)((size_t)N_ROWS * DIM);  // (beta+1)/(N*D)
        atomicAdd(loss, (lred[0] + lred[1] + lred[2] + lred[3]) * scale);
    }
}

extern "C" void kernel_launch(void* const* d_in, const int* in_sizes, int n_in,
                              void* d_out, int out_size, void* d_ws, size_t ws_size,
                              hipStream_t stream) {
    const float* x  = (const float*)d_in[0];
    const float* cb = (const float*)d_in[1];
    float* out  = (float*)d_out;
    float* loss = out + (size_t)N_ROWS * DIM;

    // x8 (8 MB, piece-layout fp8) lives in the front of d_out; the finish
    // kernel's gather fully overwrites it afterwards.
    unsigned int* x8 = (unsigned int*)d_out;

    char* ws = (char*)d_ws;
    unsigned int* cbf8 = (unsigned int*)ws;                        // 512 KB
    float* halfcn = (float*)(ws + (size_t)KCODES * 256);           // 8 KB
    float* part   = (float*)(ws + (size_t)KCODES * 256 + 8192);    // 8 MB

    prep_cb<<<KCODES / 4, 256, 0, stream>>>(cb, cbf8, halfcn, loss);
    prep_x<<<N_ROWS / 4, 256, 0, stream>>>(x, x8);
    vq_argmin<<<dim3(CG, YS), 256, 0, stream>>>((const char*)x8, (const char*)cbf8,
                                                halfcn, part);
    finish_kernel<<<N_ROWS / 256, 256, 0, stream>>>(x, cb, part, out, loss);
}

// Round 12
// 130.961 us; speedup vs baseline: 1.4112x; 1.4112x over previous
//
#include <hip/hip_runtime.h>

#define N_ROWS 32768
#define DIM    256
#define KCODES 2048
#define CSCALE 4096.0f

typedef __attribute__((ext_vector_type(16))) float f32x16;
typedef __attribute__((ext_vector_type(4)))  unsigned int u32x4;
union frag16 { u32x4 v; long l[2]; };

// pack 16 fp32 -> 16 fp8 e4m3 (4 dwords)
__device__ __forceinline__ uint4 pack16(const float* s) {
    int a = __builtin_amdgcn_cvt_pk_fp8_f32(s[0],  s[1],  0, false);
    a     = __builtin_amdgcn_cvt_pk_fp8_f32(s[2],  s[3],  a, true);
    int b = __builtin_amdgcn_cvt_pk_fp8_f32(s[4],  s[5],  0, false);
    b     = __builtin_amdgcn_cvt_pk_fp8_f32(s[6],  s[7],  b, true);
    int c = __builtin_amdgcn_cvt_pk_fp8_f32(s[8],  s[9],  0, false);
    c     = __builtin_amdgcn_cvt_pk_fp8_f32(s[10], s[11], c, true);
    int d = __builtin_amdgcn_cvt_pk_fp8_f32(s[12], s[13], 0, false);
    d     = __builtin_amdgcn_cvt_pk_fp8_f32(s[14], s[15], d, true);
    uint4 o; o.x = a; o.y = b; o.z = c; o.w = d;
    return o;
}

// Piece layout (per 64B k-chunk): piece d (=h*2+q, 16B) holds the two 8B MFMA
// fragments (ks=2q,2q+1) for k-half h:
//   bytes [0,8)  = k = q*32      + h*8 + [0,8)
//   bytes [8,16) = k = q*32 + 16 + h*8 + [0,8)

// ---------------- prologue: cb -> fp8 (x4096) piece layout + halfcn -------------
__global__ void prep_cb(const float* __restrict__ cb, unsigned int* __restrict__ cbf8,
                        float* __restrict__ halfcn, float* __restrict__ loss) {
    const int t    = threadIdx.x;            // 256 thr = 4 codes x 64 dword slots
    const int code = blockIdx.x * 4 + (t >> 6);
    const int s    = t & 63;
    if (blockIdx.x == 0 && t == 0) *loss = 0.0f;
    const int kc = s >> 4, d = (s >> 2) & 3, b4 = (s & 3) * 4;
    const int h = d >> 1, q = d & 1;
    const int k0 = kc * 64 + q * 32 + (b4 >> 3) * 16 + h * 8 + (b4 & 7);
    float4 v = *(const float4*)&cb[(size_t)code * DIM + k0];
    int pk = __builtin_amdgcn_cvt_pk_fp8_f32(v.x * CSCALE, v.y * CSCALE, 0, false);
    pk     = __builtin_amdgcn_cvt_pk_fp8_f32(v.z * CSCALE, v.w * CSCALE, pk, true);
    cbf8[(size_t)code * 64 + s] = (unsigned int)pk;
    float ssum = v.x * v.x + v.y * v.y + v.z * v.z + v.w * v.w;
    #pragma unroll
    for (int o = 32; o > 0; o >>= 1) ssum += __shfl_down(ssum, o, 64);
    if (s == 0) halfcn[code] = 0.5f * CSCALE * ssum;
}

// ---------------- fused: 64 rows x 2048 codes, codebook streams via registers ---
// x rows -> fp8 pieces in LDS (converted in-block), each lane's 2-row fragments
// then live in 64 VGPRs for the whole kernel. Codebook slices (32 codes/wave/iter)
// stream global->VGPR register-double-buffered: loads for iter g+1 issue before
// iter g's 32 MFMAs. In-lane argmax (C: n=row=lane), fused gather+loss epilogue.
__global__ __launch_bounds__(256, 2) void vq_fused(
        const float* __restrict__ x, const float* __restrict__ cb,
        const char* __restrict__ cbf8, const float* __restrict__ halfcn,
        float* __restrict__ out, float* __restrict__ loss) {
    __shared__ char mem[16384];            // x-conversion stage; reused for reductions

    const int t    = threadIdx.x;
    const int lane = t & 63;
    const int w    = t >> 6;
    const int l32  = lane & 31;
    const int h    = lane >> 5;
    const int row0 = blockIdx.x * 64;

    // ---- stage x: fp32 -> fp8 pieces into mem[kc*4096 + r*64 + p*16] ----
    {
        const int r   = t >> 2;            // row 0..63
        const int kc  = t & 3;
        const int key = (r >> 1) & 3;
        const float* src = x + (size_t)(row0 + r) * DIM + kc * 64;
        float buf[16];
        #pragma unroll
        for (int p = 0; p < 4; p++) {
            const int d = p ^ key, hh = d >> 1, qq = d & 1;
            #pragma unroll
            for (int j = 0; j < 4; j++) *(float4*)(buf + j * 4) =
                *(const float4*)(src + qq * 32 + (j >> 1) * 16 + hh * 8 + (j & 1) * 4);
            *(uint4*)(mem + kc * 4096 + r * 64 + p * 16) = pack16(buf);
        }
    }
    __syncthreads();

    // ---- x fragments -> registers (rows rt*32+l32, k-half h): 64 VGPRs ----
    const int key = (l32 >> 1) & 3;        // same key for rows l32 and 32+l32
    frag16 xf[2][4][2];
    #pragma unroll
    for (int rt = 0; rt < 2; rt++)
        #pragma unroll
        for (int kc = 0; kc < 4; kc++)
            #pragma unroll
            for (int q = 0; q < 2; q++)
                xf[rt][kc][q].v = *(const u32x4*)(mem + kc * 4096
                    + (rt * 32 + l32) * 64 + (((h * 2 + q) ^ key)) * 16);
    __syncthreads();                       // LDS free; reused at epilogue

    // ---- cg loop: 16 x (32 codes/wave), register-double-buffered cf + bias ----
    frag16 cf[2][4][2];
    float  bias[2][16];
    {
        const char* cbase = cbf8 + (size_t)(w * 32 + l32) * DIM;
        #pragma unroll
        for (int kc = 0; kc < 4; kc++)
            #pragma unroll
            for (int q = 0; q < 2; q++)
                cf[0][kc][q].v = *(const u32x4*)(cbase + kc * 64 + (h * 2 + q) * 16);
        #pragma unroll
        for (int g4 = 0; g4 < 4; g4++)
            *(float4*)&bias[0][g4 * 4] = *(const float4*)&halfcn[w * 32 + g4 * 8 + 4 * h];
    }

    float mp[2] = {-3.0e38f, -3.0e38f};

    #pragma unroll 2
    for (int g = 0; g < 16; ++g) {
        const int cur = g & 1, nxt = cur ^ 1;
        if (g < 15) {   // prefetch next code slice while this iter's MFMAs run
            const char* cbase = cbf8 + (size_t)((g + 1) * 128 + w * 32 + l32) * DIM;
            #pragma unroll
            for (int kc = 0; kc < 4; kc++)
                #pragma unroll
                for (int q = 0; q < 2; q++)
                    cf[nxt][kc][q].v = *(const u32x4*)(cbase + kc * 64 + (h * 2 + q) * 16);
            #pragma unroll
            for (int g4 = 0; g4 < 4; g4++)
                *(float4*)&bias[nxt][g4 * 4] =
                    *(const float4*)&halfcn[(g + 1) * 128 + w * 32 + g4 * 8 + 4 * h];
        }

        f32x16 acc[2];
        #pragma unroll
        for (int r = 0; r < 16; r++) { acc[0][r] = -bias[cur][r]; acc[1][r] = -bias[cur][r]; }

        #pragma unroll
        for (int kc = 0; kc < 4; kc++)
            #pragma unroll
            for (int q = 0; q < 2; q++)
                #pragma unroll
                for (int sl = 0; sl < 2; sl++)
                    #pragma unroll
                    for (int rt = 0; rt < 2; rt++)
                        acc[rt] = __builtin_amdgcn_mfma_f32_32x32x16_fp8_fp8(
                            cf[cur][kc][q].l[sl], xf[rt][kc][q].l[sl], acc[rt], 0, 0, 0);

        // in-lane fold: 16 candidate codes per lane (code id in low mantissa bits)
        const unsigned codebase = (unsigned)(g * 128 + w * 32 + 4 * h);
        #pragma unroll
        for (int rt = 0; rt < 2; rt++) {
            float best = mp[rt];
            #pragma unroll
            for (int r = 0; r < 16; r++) {
                const unsigned code = codebase + (unsigned)((r & 3) + 8 * (r >> 2));
                const unsigned u = (__float_as_uint(acc[rt][r]) & 0xFFFFF800u) | code;
                best = fmaxf(best, __uint_as_float(u));
            }
            mp[rt] = best;
        }
    }

    // ---- combine h halves, then cross-wave reduce ----
    #pragma unroll
    for (int rt = 0; rt < 2; rt++)
        mp[rt] = fmaxf(mp[rt], __shfl_xor(mp[rt], 32, 64));

    __syncthreads();                       // conversion LDS dead; reuse
    float* red  = (float*)mem;             // [64][4]
    int*   idxs = (int*)(mem + 1024);      // [64]
    float* lred = (float*)(mem + 1280);    // [4]

    if (h == 0) {
        red[(l32)      * 4 + w] = mp[0];
        red[(32 + l32) * 4 + w] = mp[1];
    }
    __syncthreads();
    if (t < 64) {
        float b0 = fmaxf(fmaxf(red[t * 4 + 0], red[t * 4 + 1]),
                         fmaxf(red[t * 4 + 2], red[t * 4 + 3]));
        idxs[t] = (int)(__float_as_uint(b0) & 2047u);
    }
    __syncthreads();

    // ---- fused gather (fp32 codebook) + loss partial ----
    float lsum = 0.0f;
    #pragma unroll 4
    for (int r = 0; r < 64; r++) {
        const int code = idxs[r];
        const float c  = cb[(size_t)code * DIM + t];
        const float xv = x[(size_t)(row0 + r) * DIM + t];
        out[(size_t)(row0 + r) * DIM + t] = c;
        const float d = xv - c;
        lsum += d * d;
    }
    #pragma unroll
    for (int o = 32; o > 0; o >>= 1) lsum += __shfl_down(lsum, o, 64);
    if (lane == 0) lred[w] = lsum;
    __syncthreads();
    if (t == 0) {
        const float scale = 1.25f / (float)((size_t)N_ROWS * DIM);  // (beta+1)/(N*D)
        atomicAdd(loss, (lred[0] + lred[1] + lred[2] + lred[3]) * scale);
    }
}

extern "C" void kernel_launch(void* const* d_in, const int* in_sizes, int n_in,
                              void* d_out, int out_size, void* d_ws, size_t ws_size,
                              hipStream_t stream) {
    const float* x  = (const float*)d_in[0];
    const float* cb = (const float*)d_in[1];
    float* out  = (float*)d_out;
    float* loss = out + (size_t)N_ROWS * DIM;

    char* ws = (char*)d_ws;
    unsigned int* cbf8 = (unsigned int*)ws;                        // 512 KB
    float* halfcn = (float*)(ws + (size_t)KCODES * 256);           // 8 KB

    prep_cb<<<KCODES / 4, 256, 0, stream>>>(cb, cbf8, halfcn, loss);
    vq_fused<<<N_ROWS / 64, 256, 0, stream>>>(x, cb, (const char*)cbf8, halfcn, out, loss);
}

// Round 13
// 126.308 us; speedup vs baseline: 1.4632x; 1.0368x over previous
//
#include <hip/hip_runtime.h>

#define N_ROWS 32768
#define DIM    256
#define KCODES 2048
#define CSCALE 4096.0f

typedef __attribute__((ext_vector_type(16))) float f32x16;
typedef __attribute__((ext_vector_type(4)))  unsigned int u32x4;
union frag16 { u32x4 v; long l[2]; };

// pack 16 fp32 -> 16 fp8 e4m3 (4 dwords)
__device__ __forceinline__ uint4 pack16(const float* s) {
    int a = __builtin_amdgcn_cvt_pk_fp8_f32(s[0],  s[1],  0, false);
    a     = __builtin_amdgcn_cvt_pk_fp8_f32(s[2],  s[3],  a, true);
    int b = __builtin_amdgcn_cvt_pk_fp8_f32(s[4],  s[5],  0, false);
    b     = __builtin_amdgcn_cvt_pk_fp8_f32(s[6],  s[7],  b, true);
    int c = __builtin_amdgcn_cvt_pk_fp8_f32(s[8],  s[9],  0, false);
    c     = __builtin_amdgcn_cvt_pk_fp8_f32(s[10], s[11], c, true);
    int d = __builtin_amdgcn_cvt_pk_fp8_f32(s[12], s[13], 0, false);
    d     = __builtin_amdgcn_cvt_pk_fp8_f32(s[14], s[15], d, true);
    uint4 o; o.x = a; o.y = b; o.z = c; o.w = d;
    return o;
}

// MFMA piece semantics (16B per lane per (kc,q), lane k-half h):
//   bytes [0,8)  = k = kc*64 + q*32      + h*8 + [0,8)   (MFMA sl=0)
//   bytes [8,16) = k = kc*64 + q*32 + 16 + h*8 + [0,8)   (MFMA sl=1)
//
// WAVE-FRAGMENT-ORDER codebook layout (the R13 change): for 32-code group g,
// piece-pair j = kc*2+q, the 1KB block cbf8[g*8192 + j*1024 + lane*16] holds
// lane (h*32+c)'s piece for code g*32+c. One dwordx4 at base+lane*16 is a fully
// coalesced (16-line) load delivering every lane its fragment directly.

// ---------------- prologue: cb -> fp8 (x4096) wave-fragment order + halfcn ------
__global__ void prep_cb(const float* __restrict__ cb, unsigned int* __restrict__ cbf8,
                        float* __restrict__ halfcn, float* __restrict__ loss) {
    const int t    = threadIdx.x;            // 256 thr = 4 codes x 64 dword slots
    const int code = blockIdx.x * 4 + (t >> 6);
    const int s    = t & 63;
    if (blockIdx.x == 0 && t == 0) *loss = 0.0f;
    const int kc = s >> 4, q = (s >> 3) & 1, h = (s >> 2) & 1, d4 = s & 3;
    const int k0 = kc * 64 + q * 32 + h * 8 + (d4 >> 1) * 16 + (d4 & 1) * 4;
    float4 v = *(const float4*)&cb[(size_t)code * DIM + k0];
    int pk = __builtin_amdgcn_cvt_pk_fp8_f32(v.x * CSCALE, v.y * CSCALE, 0, false);
    pk     = __builtin_amdgcn_cvt_pk_fp8_f32(v.z * CSCALE, v.w * CSCALE, pk, true);
    const int g = code >> 5, cm = code & 31;
    cbf8[(size_t)g * 2048 + (kc * 2 + q) * 256 + (h * 32 + cm) * 4 + d4] = (unsigned)pk;
    float ssum = v.x * v.x + v.y * v.y + v.z * v.z + v.w * v.w;  // each k once
    #pragma unroll
    for (int o = 32; o > 0; o >>= 1) ssum += __shfl_down(ssum, o, 64);
    if (s == 0) halfcn[code] = 0.5f * CSCALE * ssum;
}

// ---------------- fused: 64 rows x 2048 codes, coalesced register streaming -----
// x rows -> fp8 pieces via LDS (converted in-block), lane's 2-row fragments then
// live in 64 VGPRs. Codebook streams global->VGPR in wave-fragment order: 8
// coalesced dwordx4 per 32-code group, compiler-pipelined. In-lane argmax,
// fused gather+loss epilogue. No LDS / no barriers in the hot loop.
__global__ __launch_bounds__(256, 2) void vq_fused(
        const float* __restrict__ x, const float* __restrict__ cb,
        const char* __restrict__ cbf8, const float* __restrict__ halfcn,
        float* __restrict__ out, float* __restrict__ loss) {
    __shared__ char mem[16384];            // x-conversion stage; reused for reductions

    const int t    = threadIdx.x;
    const int lane = t & 63;
    const int w    = t >> 6;
    const int l32  = lane & 31;
    const int h    = lane >> 5;
    const int row0 = blockIdx.x * 64;

    // ---- stage x: fp32 -> fp8 pieces into mem[kc*4096 + r*64 + p*16] ----
    {
        const int r   = t >> 2;            // row 0..63
        const int kc  = t & 3;
        const int key = (r >> 1) & 3;
        const float* src = x + (size_t)(row0 + r) * DIM + kc * 64;
        float buf[16];
        #pragma unroll
        for (int p = 0; p < 4; p++) {
            const int d = p ^ key, hh = d >> 1, qq = d & 1;
            #pragma unroll
            for (int j = 0; j < 4; j++) *(float4*)(buf + j * 4) =
                *(const float4*)(src + qq * 32 + (j >> 1) * 16 + hh * 8 + (j & 1) * 4);
            *(uint4*)(mem + kc * 4096 + r * 64 + p * 16) = pack16(buf);
        }
    }
    __syncthreads();

    // ---- x fragments -> registers (rows rt*32+l32, k-half h): 64 VGPRs ----
    const int key = (l32 >> 1) & 3;
    frag16 xf[2][4][2];
    #pragma unroll
    for (int rt = 0; rt < 2; rt++)
        #pragma unroll
        for (int kc = 0; kc < 4; kc++)
            #pragma unroll
            for (int q = 0; q < 2; q++)
                xf[rt][kc][q].v = *(const u32x4*)(mem + kc * 4096
                    + (rt * 32 + l32) * 64 + (((h * 2 + q) ^ key)) * 16);
    __syncthreads();                       // LDS free; reused at epilogue

    float mp[2] = {-3.0e38f, -3.0e38f};

    // ---- 16 iterations: wave w handles code groups g = w + 4*i ----
    for (int i = 0; i < 16; ++i) {
        const int g = w + 4 * i;

        // 8 fully-coalesced dwordx4: the wave's 32-code fragment block (8 KB)
        frag16 cf[8];
        const char* gbase = cbf8 + (size_t)g * 8192 + lane * 16;
        #pragma unroll
        for (int j = 0; j < 8; j++)
            cf[j].v = *(const u32x4*)(gbase + j * 1024);

        // bias (broadcast loads, 1-2 lines each)
        float bias[16];
        #pragma unroll
        for (int g4 = 0; g4 < 4; g4++)
            *(float4*)&bias[g4 * 4] = *(const float4*)&halfcn[g * 32 + g4 * 8 + 4 * h];

        f32x16 acc[2];
        #pragma unroll
        for (int r = 0; r < 16; r++) { acc[0][r] = -bias[r]; acc[1][r] = -bias[r]; }

        #pragma unroll
        for (int kc = 0; kc < 4; kc++)
            #pragma unroll
            for (int q = 0; q < 2; q++)
                #pragma unroll
                for (int sl = 0; sl < 2; sl++)
                    #pragma unroll
                    for (int rt = 0; rt < 2; rt++)
                        acc[rt] = __builtin_amdgcn_mfma_f32_32x32x16_fp8_fp8(
                            cf[kc * 2 + q].l[sl], xf[rt][kc][q].l[sl], acc[rt], 0, 0, 0);

        // in-lane fold: 16 candidate codes per lane (code id in low mantissa bits)
        const unsigned codebase = (unsigned)(g * 32 + 4 * h);
        #pragma unroll
        for (int rt = 0; rt < 2; rt++) {
            float best = mp[rt];
            #pragma unroll
            for (int r = 0; r < 16; r++) {
                const unsigned code = codebase + (unsigned)((r & 3) + 8 * (r >> 2));
                const unsigned u = (__float_as_uint(acc[rt][r]) & 0xFFFFF800u) | code;
                best = fmaxf(best, __uint_as_float(u));
            }
            mp[rt] = best;
        }
    }

    // ---- combine h halves, then cross-wave reduce ----
    #pragma unroll
    for (int rt = 0; rt < 2; rt++)
        mp[rt] = fmaxf(mp[rt], __shfl_xor(mp[rt], 32, 64));

    __syncthreads();                       // conversion LDS dead; reuse
    float* red  = (float*)mem;             // [64][4]
    int*   idxs = (int*)(mem + 1024);      // [64]
    float* lred = (float*)(mem + 1280);    // [4]

    if (h == 0) {
        red[(l32)      * 4 + w] = mp[0];
        red[(32 + l32) * 4 + w] = mp[1];
    }
    __syncthreads();
    if (t < 64) {
        float b0 = fmaxf(fmaxf(red[t * 4 + 0], red[t * 4 + 1]),
                         fmaxf(red[t * 4 + 2], red[t * 4 + 3]));
        idxs[t] = (int)(__float_as_uint(b0) & 2047u);
    }
    __syncthreads();

    // ---- fused gather (fp32 codebook) + loss partial ----
    float lsum = 0.0f;
    #pragma unroll 4
    for (int r = 0; r < 64; r++) {
        const int code = idxs[r];
        const float c  = cb[(size_t)code * DIM + t];
        const float xv = x[(size_t)(row0 + r) * DIM + t];
        out[(size_t)(row0 + r) * DIM + t] = c;
        const float d = xv - c;
        lsum += d * d;
    }
    #pragma unroll
    for (int o = 32; o > 0; o >>= 1) lsum += __shfl_down(lsum, o, 64);
    if (lane == 0) lred[w] = lsum;
    __syncthreads();
    if (t == 0) {
        const float scale = 1.25f / (float)((size_t)N_ROWS * DIM);  // (beta+1)/(N*D)
        atomicAdd(loss, (lred[0] + lred[1] + lred[2] + lred[3]) * scale);
    }
}

extern "C" void kernel_launch(void* const* d_in, const int* in_sizes, int n_in,
                              void* d_out, int out_size, void* d_ws, size_t ws_size,
                              hipStream_t stream) {
    const float* x  = (const float*)d_in[0];
    const float* cb = (const float*)d_in[1];
    float* out  = (float*)d_out;
    float* loss = out + (size_t)N_ROWS * DIM;

    char* ws = (char*)d_ws;
    unsigned int* cbf8 = (unsigned int*)ws;                        // 512 KB
    float* halfcn = (float*)(ws + (size_t)KCODES * 256);           // 8 KB

    prep_cb<<<KCODES / 4, 256, 0, stream>>>(cb, cbf8, halfcn, loss);
    vq_fused<<<N_ROWS / 64, 256, 0, stream>>>(x, cb, (const char*)cbf8, halfcn, out, loss);
}